// Round 5
// baseline (1104.011 us; speedup 1.0000x reference)
//
#include <hip/hip_runtime.h>
#include <cstddef>
#include <cstdint>

#define S3 32768  // 32*32*32 spatial positions

typedef short bf16x8 __attribute__((ext_vector_type(8)));   // 8 bf16 in 4 VGPRs
typedef float f32x16 __attribute__((ext_vector_type(16)));

static __device__ inline unsigned short f2bf(float f) {
    unsigned int u = __float_as_uint(f);
    unsigned int r = (u + 0x7FFFu + ((u >> 16) & 1u)) >> 16;  // RNE
    return (unsigned short)r;
}

// --------- weight transpose: wT[tap][icb][c][kb][chunk(ln*2+half)][8ic] ----
// One A-fragment (tap,icb,c,kb) = 64 chunks * 16 B = 1 KB, lane-dense.
template <int IC, int OC>
__global__ __launch_bounds__(256) void wt_transpose(
    const float* __restrict__ w, unsigned short* __restrict__ wT)
{
    int t = blockIdx.x * 256 + threadIdx.x;  // < 125*IC*OC
    int e = t & 7;
    int chunk = (t >> 3) & 63;
    int kb = (t >> 9) & 1;
    int rest = t >> 10;                       // (tap*ICB + icb)*NOC + c
    int c = rest % (OC / 32); rest /= (OC / 32);
    int icb = rest % (IC / 32);
    int tap = rest / (IC / 32);
    int ln = chunk >> 1, half = chunk & 1;
    int oc = c * 32 + ln;
    int ic = icb * 32 + kb * 16 + half * 8 + e;
    wT[t] = f2bf(w[((size_t)oc * IC + ic) * 125 + tap]);
}

// ---------------- x transpose: xb[b][z][y][x][128 ic] bf16 -----------------
__global__ __launch_bounds__(256) void xb_transpose(
    const float* __restrict__ x, unsigned short* __restrict__ xb)
{
    __shared__ float tile[32][133];
    int zy = blockIdx.x, b = blockIdx.y;
    int t = threadIdx.x, xi = t & 31, ich = t >> 5;
#pragma unroll
    for (int k = 0; k < 16; ++k) {
        int ic = k * 8 + ich;
        tile[xi][ic] = x[(size_t)(b * 128 + ic) * S3 + zy * 32 + xi];
    }
    __syncthreads();
#pragma unroll
    for (int k = 0; k < 2; ++k) {
        int u = t + 256 * k;
        int xx = u >> 4, j = u & 15;
        __align__(16) unsigned short tmp[8];
#pragma unroll
        for (int e = 0; e < 8; ++e) tmp[e] = f2bf(tile[xx][j * 8 + e]);
        *(uint4*)(xb + ((size_t)b * S3 + zy * 32 + xx) * 128 + j * 8) =
            *(const uint4*)tmp;
    }
}

// ---------------- attention (row 4 only), writes alpha*att into d_out ------
__global__ __launch_bounds__(256) void attention_kernel(
    const float* __restrict__ x, const float* __restrict__ basis,
    const float* __restrict__ mixer, const float* __restrict__ wq,
    const float* __restrict__ wk, const float* __restrict__ wv,
    const float* __restrict__ alpha_p, float* __restrict__ out)
{
    int t = blockIdx.x * 256 + threadIdx.x;
    int s = t & (S3 - 1);
    int b = t >> 15;

    float tok[32];
#pragma unroll
    for (int c = 0; c < 32; ++c) tok[c] = 0.f;
#pragma unroll
    for (int r = 0; r < 8; ++r) {
        float bv = basis[r * S3 + s];
#pragma unroll
        for (int c = 0; c < 32; ++c) tok[c] += mixer[c * 8 + r] * bv;
    }
    const float* wq4 = wq + 4 * 1024;
    float q[32];
#pragma unroll
    for (int o = 0; o < 32; ++o) {
        float a = 0.f;
#pragma unroll
        for (int c = 0; c < 32; ++c) a += wq4[o * 32 + c] * tok[c];
        q[o] = a;
    }

    const float scale = 0.17677669529663687f;
    float l[5];
#pragma unroll
    for (int j = 0; j < 5; ++j) {
        float xv[32];
        const float* xp = (j < 4) ? (x + ((size_t)b * 128 + j * 32) * S3) : nullptr;
#pragma unroll
        for (int c = 0; c < 32; ++c) xv[c] = (j < 4) ? xp[(size_t)c * S3 + s] : tok[c];
        const float* wkj = wk + j * 1024;
        float acc = 0.f;
#pragma unroll
        for (int o = 0; o < 32; ++o) {
            float kv = 0.f;
#pragma unroll
            for (int c = 0; c < 32; ++c) kv += wkj[o * 32 + c] * xv[c];
            acc += q[o] * kv;
        }
        l[j] = acc * scale;
    }
    float m = l[0];
#pragma unroll
    for (int j = 1; j < 5; ++j) m = fmaxf(m, l[j]);
    float p[5], sum = 0.f;
#pragma unroll
    for (int j = 0; j < 5; ++j) { p[j] = __expf(l[j] - m); sum += p[j]; }
    float inv = alpha_p[0] / sum;

    float ov[32];
#pragma unroll
    for (int o = 0; o < 32; ++o) ov[o] = 0.f;
#pragma unroll
    for (int j = 0; j < 5; ++j) {
        float xv[32];
        const float* xp = (j < 4) ? (x + ((size_t)b * 128 + j * 32) * S3) : nullptr;
#pragma unroll
        for (int c = 0; c < 32; ++c) xv[c] = (j < 4) ? xp[(size_t)c * S3 + s] : tok[c];
        const float* wvj = wv + j * 1024;
        float pj = p[j];
#pragma unroll
        for (int o = 0; o < 32; ++o) {
            float vv = 0.f;
#pragma unroll
            for (int c = 0; c < 32; ++c) vv += wvj[o * 32 + c] * xv[c];
            ov[o] += pj * vv;
        }
    }
#pragma unroll
    for (int o = 0; o < 32; ++o)
        out[((size_t)b * 32 + o) * S3 + s] = ov[o] * inv;
}

// ---------------- implicit-GEMM 5x5x5 conv via MFMA 32x32x16 bf16 ----------
// Block: OC x (16 y x 32 x) at one z; 4 waves, wave-tile OC x 4 y-rows.
// A (weights) loaded per-frag direct from global (L2-resident, lane-dense 1KB).
// B (input) from LDS; 8 rows cached in regs per (dx,kb), reused across dy.
// Input staged via register prefetch issued inside previous MFMA section.
// xin: [b][z][y][x][IC] bf16. wT: [tap][icb][c][kb][64 chunks][8ic] bf16.
template <int IC, int OC, bool WRITE_H>
__global__ __launch_bounds__(256, 1) void conv_mfma(
    const unsigned short* __restrict__ xin, const uint4* __restrict__ wTq,
    const float* __restrict__ bias, unsigned short* __restrict__ hout,
    float* __restrict__ fout)
{
    constexpr int NOC = OC / 32, ICB = IC / 32;
    constexpr int JT = 4, NROW = 20;
    __shared__ __align__(16) char lds_in[NROW * 36 * 80];  // 57.6 KB

    const int tid = threadIdx.x;
    const int wave = tid >> 6, lane = tid & 63;
    const int ln = lane & 31, half = lane >> 5;
    const int z = blockIdx.x, ybl = blockIdx.y, b = blockIdx.z;
    const int y0 = ybl * 16;

    const uint4* wTl = wTq + ln * 2 + half;  // lane-fixed chunk offset

    f32x16 acc[NOC][JT];
#pragma unroll
    for (int c = 0; c < NOC; ++c)
#pragma unroll
        for (int j = 0; j < JT; ++j)
#pragma unroll
            for (int e = 0; e < 16; ++e) acc[c][j][e] = 0.f;

    uint4 pre[12];  // staging prefetch: 2880 uint4 / 256 threads

    auto issue = [&](int icb, int dz) {
        int gz = z + dz - 2;
        bool zok = (unsigned)gz < 32u;
#pragma unroll
        for (int k = 0; k < 12; ++k) {
            int i = tid + 256 * k;
            if (i < 2880) {
                int sub = i & 3, cc = i >> 2;
                int x36 = cc % 36, row = cc / 36;
                int gy = y0 - 2 + row, gx = x36 - 2;
                uint4 v = {0u, 0u, 0u, 0u};
                if (zok && (unsigned)gy < 32u && (unsigned)gx < 32u)
                    v = *(const uint4*)(xin +
                        ((((size_t)b * 32 + gz) * 32 + gy) * 32 + gx) * IC +
                        icb * 32 + sub * 8);
                pre[k] = v;
            }
        }
    };

    issue(0, 0);
    for (int icb = 0; icb < ICB; ++icb) {
        for (int dz = 0; dz < 5; ++dz) {
            __syncthreads();  // previous MFMA section done reading lds_in
#pragma unroll
            for (int k = 0; k < 12; ++k) {
                int i = tid + 256 * k;
                if (i < 2880) {
                    int sub = i & 3, cc = i >> 2;
                    int x36 = cc % 36, row = cc / 36;
                    *(uint4*)(lds_in + row * 2880 + x36 * 80 + sub * 16) = pre[k];
                }
            }
            __syncthreads();  // staging visible

            const int nxt = icb * 5 + dz + 1;
#pragma unroll
            for (int dx = 0; dx < 5; ++dx) {
#pragma unroll
                for (int kb = 0; kb < 2; ++kb) {
                    bf16x8 brow[8];
#pragma unroll
                    for (int r = 0; r < 8; ++r)
                        brow[r] = *(const bf16x8*)(lds_in +
                            (JT * wave + r) * 2880 + (ln + dx) * 80 +
                            kb * 32 + half * 16);
                    // prefetch next staging after first MFMA group issued its
                    // A-loads, so A waits don't drain the staging queue
                    if (dx == 0 && kb == 1 && nxt < ICB * 5) issue(nxt / 5, nxt % 5);
#pragma unroll
                    for (int dy = 0; dy < 5; ++dy) {
                        int tap = (dz * 5 + dy) * 5 + dx;
#pragma unroll
                        for (int c = 0; c < NOC; ++c) {
                            bf16x8 a = *(const bf16x8*)(wTl +
                                (size_t)(((tap * ICB + icb) * NOC + c) * 2 + kb) * 64);
#pragma unroll
                            for (int j = 0; j < JT; ++j)
                                acc[c][j] = __builtin_amdgcn_mfma_f32_32x32x16_bf16(
                                    a, brow[dy + j], acc[c][j], 0, 0, 0);
                        }
                    }
                }
            }
        }
    }

    __syncthreads();
    if (WRITE_H) {
        // bias + exact GELU, transpose to [x][oc] via per-wave LDS scratch,
        // store h[b][z][y][x][OC] bf16 (conv2's staging layout).
        char* scr = lds_in + wave * (32 * 144);
#pragma unroll
        for (int j = 0; j < JT; ++j) {
            int y = y0 + JT * wave + j;
#pragma unroll
            for (int c = 0; c < NOC; ++c)
#pragma unroll
                for (int r = 0; r < 16; ++r) {
                    int oc = c * 32 + (r & 3) + 8 * (r >> 2) + 4 * half;
                    float v = acc[c][j][r] + bias[oc];
                    v = 0.5f * v * (1.f + erff(v * 0.70710678118654752f));
                    *(unsigned short*)(scr + ln * 144 + oc * 2) = f2bf(v);
                }
            __syncthreads();
#pragma unroll
            for (int k = 0; k < OC / 16; ++k) {
                int u = lane + 64 * k;          // 16B units, OC/8 per x
                int xx = u / (OC / 8), un = u % (OC / 8);
                uint4 v = *(const uint4*)(scr + xx * 144 + un * 16);
                *(uint4*)(hout + ((((size_t)b * 32 + z) * 32 + y) * 32 + xx) * OC +
                          un * 8) = v;
            }
            __syncthreads();
        }
    } else {
        // final: bias + attention (already alpha-scaled in fout) added in place
#pragma unroll
        for (int j = 0; j < JT; ++j) {
            int y = y0 + JT * wave + j;
#pragma unroll
            for (int r = 0; r < 16; ++r) {
                int oc = (r & 3) + 8 * (r >> 2) + 4 * half;
                size_t o = ((size_t)b * OC + oc) * S3 + z * 1024 + y * 32 + ln;
                fout[o] = acc[0][j][r] + bias[oc] + fout[o];
            }
        }
    }
}

// ---------------------------------------------------------------------------
extern "C" void kernel_launch(void* const* d_in, const int* in_sizes, int n_in,
                              void* d_out, int out_size, void* d_ws, size_t ws_size,
                              hipStream_t stream)
{
    const float* x       = (const float*)d_in[0];
    const float* basis   = (const float*)d_in[1];
    const float* mixer   = (const float*)d_in[2];
    const float* wq      = (const float*)d_in[3];
    const float* wk      = (const float*)d_in[4];
    const float* wv      = (const float*)d_in[5];
    const float* conv1_w = (const float*)d_in[6];
    const float* conv1_b = (const float*)d_in[7];
    const float* conv2_w = (const float*)d_in[8];
    const float* conv2_b = (const float*)d_in[9];
    const float* alpha   = (const float*)d_in[10];
    float* out = (float*)d_out;

    char* wsb = (char*)d_ws;
    unsigned short* xb  = (unsigned short*)wsb;               // 32 MiB
    unsigned short* h   = (unsigned short*)(wsb + 33554432);  // 16 MiB
    unsigned short* wT1 = (unsigned short*)(wsb + 50331648);  // 2 MiB
    unsigned short* wT2 = (unsigned short*)(wsb + 52379648);  // 0.5 MiB

    wt_transpose<128, 64><<<4000, 256, 0, stream>>>(conv1_w, wT1);
    wt_transpose<64, 32><<<1000, 256, 0, stream>>>(conv2_w, wT2);
    xb_transpose<<<dim3(1024, 4), 256, 0, stream>>>(x, xb);

    attention_kernel<<<512, 256, 0, stream>>>(x, basis, mixer, wq, wk, wv,
                                              alpha, out);

    conv_mfma<128, 64, true><<<dim3(32, 2, 4), 256, 0, stream>>>(
        xb, (const uint4*)wT1, conv1_b, h, nullptr);
    conv_mfma<64, 32, false><<<dim3(32, 2, 4), 256, 0, stream>>>(
        h, (const uint4*)wT2, conv2_b, nullptr, out);
}

// Round 6
// 688.620 us; speedup vs baseline: 1.6032x; 1.6032x over previous
//
#include <hip/hip_runtime.h>
#include <cstddef>
#include <cstdint>

#define S3 32768  // 32*32*32 spatial positions

typedef short bf16x8 __attribute__((ext_vector_type(8)));   // 8 bf16 in 4 VGPRs
typedef float f32x16 __attribute__((ext_vector_type(16)));

static __device__ inline unsigned short f2bf(float f) {
    unsigned int u = __float_as_uint(f);
    unsigned int r = (u + 0x7FFFu + ((u >> 16) & 1u)) >> 16;  // RNE
    return (unsigned short)r;
}

// --------- weight transpose: wT[tap][icb][c][kb][chunk(ln*2+half)][8ic] ----
// One A-fragment (tap,icb,c,kb) = 64 chunks * 16 B = 1 KB, lane-dense.
template <int IC, int OC>
__global__ __launch_bounds__(256) void wt_transpose(
    const float* __restrict__ w, unsigned short* __restrict__ wT)
{
    int t = blockIdx.x * 256 + threadIdx.x;  // < 125*IC*OC
    int e = t & 7;
    int chunk = (t >> 3) & 63;
    int kb = (t >> 9) & 1;
    int rest = t >> 10;                       // (tap*ICB + icb)*NOC + c
    int c = rest % (OC / 32); rest /= (OC / 32);
    int icb = rest % (IC / 32);
    int tap = rest / (IC / 32);
    int ln = chunk >> 1, half = chunk & 1;
    int oc = c * 32 + ln;
    int ic = icb * 32 + kb * 16 + half * 8 + e;
    wT[t] = f2bf(w[((size_t)oc * IC + ic) * 125 + tap]);
}

// ---------------- x transpose: xb[b][z][y][x][128 ic] bf16 -----------------
__global__ __launch_bounds__(256) void xb_transpose(
    const float* __restrict__ x, unsigned short* __restrict__ xb)
{
    __shared__ float tile[32][133];
    int zy = blockIdx.x, b = blockIdx.y;
    int t = threadIdx.x, xi = t & 31, ich = t >> 5;
#pragma unroll
    for (int k = 0; k < 16; ++k) {
        int ic = k * 8 + ich;
        tile[xi][ic] = x[(size_t)(b * 128 + ic) * S3 + zy * 32 + xi];
    }
    __syncthreads();
#pragma unroll
    for (int k = 0; k < 2; ++k) {
        int u = t + 256 * k;
        int xx = u >> 4, j = u & 15;
        __align__(16) unsigned short tmp[8];
#pragma unroll
        for (int e = 0; e < 8; ++e) tmp[e] = f2bf(tile[xx][j * 8 + e]);
        *(uint4*)(xb + ((size_t)b * S3 + zy * 32 + xx) * 128 + j * 8) =
            *(const uint4*)tmp;
    }
}

// ---------------- attention (row 4 only), writes alpha*att into d_out ------
__global__ __launch_bounds__(256) void attention_kernel(
    const float* __restrict__ x, const float* __restrict__ basis,
    const float* __restrict__ mixer, const float* __restrict__ wq,
    const float* __restrict__ wk, const float* __restrict__ wv,
    const float* __restrict__ alpha_p, float* __restrict__ out)
{
    int t = blockIdx.x * 256 + threadIdx.x;
    int s = t & (S3 - 1);
    int b = t >> 15;

    float tok[32];
#pragma unroll
    for (int c = 0; c < 32; ++c) tok[c] = 0.f;
#pragma unroll
    for (int r = 0; r < 8; ++r) {
        float bv = basis[r * S3 + s];
#pragma unroll
        for (int c = 0; c < 32; ++c) tok[c] += mixer[c * 8 + r] * bv;
    }
    const float* wq4 = wq + 4 * 1024;
    float q[32];
#pragma unroll
    for (int o = 0; o < 32; ++o) {
        float a = 0.f;
#pragma unroll
        for (int c = 0; c < 32; ++c) a += wq4[o * 32 + c] * tok[c];
        q[o] = a;
    }

    const float scale = 0.17677669529663687f;
    float l[5];
#pragma unroll
    for (int j = 0; j < 5; ++j) {
        float xv[32];
        const float* xp = (j < 4) ? (x + ((size_t)b * 128 + j * 32) * S3) : nullptr;
#pragma unroll
        for (int c = 0; c < 32; ++c) xv[c] = (j < 4) ? xp[(size_t)c * S3 + s] : tok[c];
        const float* wkj = wk + j * 1024;
        float acc = 0.f;
#pragma unroll
        for (int o = 0; o < 32; ++o) {
            float kv = 0.f;
#pragma unroll
            for (int c = 0; c < 32; ++c) kv += wkj[o * 32 + c] * xv[c];
            acc += q[o] * kv;
        }
        l[j] = acc * scale;
    }
    float m = l[0];
#pragma unroll
    for (int j = 1; j < 5; ++j) m = fmaxf(m, l[j]);
    float p[5], sum = 0.f;
#pragma unroll
    for (int j = 0; j < 5; ++j) { p[j] = __expf(l[j] - m); sum += p[j]; }
    float inv = alpha_p[0] / sum;

    float ov[32];
#pragma unroll
    for (int o = 0; o < 32; ++o) ov[o] = 0.f;
#pragma unroll
    for (int j = 0; j < 5; ++j) {
        float xv[32];
        const float* xp = (j < 4) ? (x + ((size_t)b * 128 + j * 32) * S3) : nullptr;
#pragma unroll
        for (int c = 0; c < 32; ++c) xv[c] = (j < 4) ? xp[(size_t)c * S3 + s] : tok[c];
        const float* wvj = wv + j * 1024;
        float pj = p[j];
#pragma unroll
        for (int o = 0; o < 32; ++o) {
            float vv = 0.f;
#pragma unroll
            for (int c = 0; c < 32; ++c) vv += wvj[o * 32 + c] * xv[c];
            ov[o] += pj * vv;
        }
    }
#pragma unroll
    for (int o = 0; o < 32; ++o)
        out[((size_t)b * 32 + o) * S3 + s] = ov[o] * inv;
}

// ---------------- implicit-GEMM 5x5x5 conv via MFMA 32x32x16 bf16 ----------
// Block: OC x (8 y x 32 x) at one z; 4 waves, wave-tile OC x 2 y-rows.
// Input in LDS (34.6 KB, register-prefetched). Weights direct from global
// (L2-resident, lane-dense 1KB frags) via register DOUBLE-BUFFER: group
// (dx,kb)'s frags load during previous group's 20 MFMAs. B-rows cached in
// regs per (dx,kb), reused across all 5 dy. Only 2 barriers per window.
// xin: [b][z][y][x][IC] bf16. wT: [tap][icb][c][kb][64 chunks][8ic] bf16.
template <int IC, int OC, bool WRITE_H>
__global__ __launch_bounds__(256, 2) void conv_mfma(
    const unsigned short* __restrict__ xin, const uint4* __restrict__ wTq,
    const float* __restrict__ bias, unsigned short* __restrict__ hout,
    float* __restrict__ fout)
{
    constexpr int NOC = OC / 32, ICB = IC / 32;
    constexpr int JT = 2, NROW = 12, NW = ICB * 5;
    constexpr int NIN = NROW * 36 * 4;  // 1728 uint4 staged per window
    __shared__ __align__(16) char lds_in[NROW * 36 * 80];  // 34.56 KB

    const int tid = threadIdx.x;
    const int wave = tid >> 6, lane = tid & 63;
    const int ln = lane & 31, half = lane >> 5;
    const int z = blockIdx.x, ybl = blockIdx.y, b = blockIdx.z;
    const int y0 = ybl * 8;

    const uint4* wTl = wTq + ln * 2 + half;  // lane-fixed chunk offset

    f32x16 acc[NOC][JT];
#pragma unroll
    for (int c = 0; c < NOC; ++c)
#pragma unroll
        for (int j = 0; j < JT; ++j)
#pragma unroll
            for (int e = 0; e < 16; ++e) acc[c][j][e] = 0.f;

    uint4 pre[7];  // input prefetch: 1728 uint4 / 256 threads

    auto issue = [&](int icb, int dz) {
        int gz = z + dz - 2;
        bool zok = (unsigned)gz < 32u;
#pragma unroll
        for (int k = 0; k < 7; ++k) {
            int i = tid + 256 * k;
            if (i < NIN) {
                int sub = i & 3, cc = i >> 2;
                int x36 = cc % 36, row = cc / 36;
                int gy = y0 - 2 + row, gx = x36 - 2;
                uint4 v = {0u, 0u, 0u, 0u};
                if (zok && (unsigned)gy < 32u && (unsigned)gx < 32u)
                    v = *(const uint4*)(xin +
                        ((((size_t)b * 32 + gz) * 32 + gy) * 32 + gx) * IC +
                        icb * 32 + sub * 8);
                pre[k] = v;
            }
        }
    };

    bf16x8 bufA[5][NOC], bufB[5][NOC];

    auto fillA = [&](bool valid, int icb, int dz, int dx, int kb,
                     bf16x8 (&buf)[5][NOC]) {
        if (!valid) return;
#pragma unroll
        for (int dy = 0; dy < 5; ++dy) {
            int tap = (dz * 5 + dy) * 5 + dx;
#pragma unroll
            for (int c = 0; c < NOC; ++c) {
                int f = ((tap * ICB + icb) * NOC + c) * 2 + kb;
                buf[dy][c] = *(const bf16x8*)(wTl + (size_t)f * 64);
            }
        }
    };

    auto compute = [&](bf16x8 (&cur)[5][NOC], int dx, int kb) {
        bf16x8 brow[JT + 4];
#pragma unroll
        for (int r = 0; r < JT + 4; ++r)
            brow[r] = *(const bf16x8*)(lds_in + (JT * wave + r) * 2880 +
                                       (ln + dx) * 80 + kb * 32 + half * 16);
#pragma unroll
        for (int dy = 0; dy < 5; ++dy)
#pragma unroll
            for (int c = 0; c < NOC; ++c)
#pragma unroll
                for (int j = 0; j < JT; ++j)
                    acc[c][j] = __builtin_amdgcn_mfma_f32_32x32x16_bf16(
                        cur[dy][c], brow[dy + j], acc[c][j], 0, 0, 0);
    };

    issue(0, 0);
    fillA(true, 0, 0, 0, 0, bufA);

    for (int w = 0; w < NW; ++w) {
        int icb = w / 5, dz = w - icb * 5;
        int nw = w + 1;
        int nicb = nw / 5, ndz = nw - nicb * 5;
        bool more = nw < NW;

        __syncthreads();  // previous window's readers done
#pragma unroll
        for (int k = 0; k < 7; ++k) {
            int i = tid + 256 * k;
            if (i < NIN) {
                int sub = i & 3, cc = i >> 2;
                int x36 = cc % 36, row = cc / 36;
                *(uint4*)(lds_in + row * 2880 + x36 * 80 + sub * 16) = pre[k];
            }
        }
        __syncthreads();  // staging visible

#pragma unroll
        for (int gp = 0; gp < 5; ++gp) {
            // even group g=2*gp: consume bufA, fill bufB with (dx=gp, kb=1)
            fillA(true, icb, dz, gp, 1, bufB);
            compute(bufA, gp, 0);
            // odd group g=2*gp+1: consume bufB, fill bufA with next group
            if (gp < 4) fillA(true, icb, dz, gp + 1, 0, bufA);
            else        fillA(more, nicb, ndz, 0, 0, bufA);
            if (gp == 0) { if (more) issue(nicb, ndz); }
            compute(bufB, gp, 1);
        }
    }

    __syncthreads();
    if (WRITE_H) {
        // bias + exact GELU, transpose to [x][oc] via per-wave LDS scratch,
        // store h[b][z][y][x][OC] bf16 (conv2's staging layout).
        char* scr = lds_in + wave * (32 * 144);
#pragma unroll
        for (int j = 0; j < JT; ++j) {
            int y = y0 + JT * wave + j;
#pragma unroll
            for (int c = 0; c < NOC; ++c)
#pragma unroll
                for (int r = 0; r < 16; ++r) {
                    int oc = c * 32 + (r & 3) + 8 * (r >> 2) + 4 * half;
                    float v = acc[c][j][r] + bias[oc];
                    v = 0.5f * v * (1.f + erff(v * 0.70710678118654752f));
                    *(unsigned short*)(scr + ln * 144 + oc * 2) = f2bf(v);
                }
            __syncthreads();
#pragma unroll
            for (int k = 0; k < OC / 16; ++k) {
                int u = lane + 64 * k;          // 16B units, OC/8 per x
                int xx = u / (OC / 8), un = u % (OC / 8);
                uint4 v = *(const uint4*)(scr + xx * 144 + un * 16);
                *(uint4*)(hout + ((((size_t)b * 32 + z) * 32 + y) * 32 + xx) * OC +
                          un * 8) = v;
            }
            __syncthreads();
        }
    } else {
        // final: bias + attention (already alpha-scaled in fout) added in place
#pragma unroll
        for (int j = 0; j < JT; ++j) {
            int y = y0 + JT * wave + j;
#pragma unroll
            for (int r = 0; r < 16; ++r) {
                int oc = (r & 3) + 8 * (r >> 2) + 4 * half;
                size_t o = ((size_t)b * OC + oc) * S3 + z * 1024 + y * 32 + ln;
                fout[o] = acc[0][j][r] + bias[oc] + fout[o];
            }
        }
    }
}

// ---------------------------------------------------------------------------
extern "C" void kernel_launch(void* const* d_in, const int* in_sizes, int n_in,
                              void* d_out, int out_size, void* d_ws, size_t ws_size,
                              hipStream_t stream)
{
    const float* x       = (const float*)d_in[0];
    const float* basis   = (const float*)d_in[1];
    const float* mixer   = (const float*)d_in[2];
    const float* wq      = (const float*)d_in[3];
    const float* wk      = (const float*)d_in[4];
    const float* wv      = (const float*)d_in[5];
    const float* conv1_w = (const float*)d_in[6];
    const float* conv1_b = (const float*)d_in[7];
    const float* conv2_w = (const float*)d_in[8];
    const float* conv2_b = (const float*)d_in[9];
    const float* alpha   = (const float*)d_in[10];
    float* out = (float*)d_out;

    char* wsb = (char*)d_ws;
    unsigned short* xb  = (unsigned short*)wsb;               // 32 MiB
    unsigned short* h   = (unsigned short*)(wsb + 33554432);  // 16 MiB
    unsigned short* wT1 = (unsigned short*)(wsb + 50331648);  // 2 MiB
    unsigned short* wT2 = (unsigned short*)(wsb + 52379648);  // 0.5 MiB

    wt_transpose<128, 64><<<4000, 256, 0, stream>>>(conv1_w, wT1);
    wt_transpose<64, 32><<<1000, 256, 0, stream>>>(conv2_w, wT2);
    xb_transpose<<<dim3(1024, 4), 256, 0, stream>>>(x, xb);

    attention_kernel<<<512, 256, 0, stream>>>(x, basis, mixer, wq, wk, wv,
                                              alpha, out);

    conv_mfma<128, 64, true><<<dim3(32, 4, 4), 256, 0, stream>>>(
        xb, (const uint4*)wT1, conv1_b, h, nullptr);
    conv_mfma<64, 32, false><<<dim3(32, 4, 4), 256, 0, stream>>>(
        h, (const uint4*)wT2, conv2_b, nullptr, out);
}